// Round 13
// baseline (837.824 us; speedup 1.0000x reference)
//
#include <hip/hip_runtime.h>
#include <hip/hip_bf16.h>
#include <cmath>

// Problem: N=64, T=512, D=512, H=512
//   xw = x @ Wx + b ; h_t = tanh(xw_t + h_{t-1} @ Wh)
//
// R13 = R12 (self-fused ring, 793us total) minus the interleave overhead:
//  - wstage ELIMINATED: each thread's Wx chunk (8 x float2 = 16 regs) loads
//    directly from L2, double-buffered one step ahead. R12 staged it through
//    LDS where all 8 waves read IDENTICAL values (32KB/step/wg ds traffic +
//    lgkmcnt on the barrier) -- pure overhead for a 16-float/thread slice.
//  - prologue software-pipelined (prefetch chunk u+1 during chunk u): R12
//    stalled on HBM every prologue iteration (~19us -> ~6us).
//  - X staging stays in LDS (rows are wave-shared, broadcast reads).
// Ring protocol + GEMM FMA order are IDENTICAL to R12 => bit-identical output.
// DEAD ENDS (do not revisit): L2 exchange (R6 sc0 / R8 wg-RMW), 2-seq
// interleave (R7), contribution-passing (R9), drain-free barrier + pipelined
// polls (R10), separate gated producer grid (R11 -- deadlocked).

#define DH     512
#define NSEQ   64
#define TSTEPS 512
#define MTOT   32768   // N*T

typedef float v2f __attribute__((ext_vector_type(2)));

// 8k-chunk GEMM micro-tile: accg[8][2] += xstage[SB] (rows rg*8..+8) x w_cur
// (FMA order identical to R12's GEMM_CHUNK)
#define GEMM_CHUNK_REG(SB)                                                     \
    {                                                                          \
        _Pragma("unroll")                                                      \
        for (int r = 0; r < 8; ++r) {                                          \
            const float4 xa = *(const float4*)&xstage[SB][rg * 8 + r][0];      \
            const float4 xb = *(const float4*)&xstage[SB][rg * 8 + r][4];      \
            accg[r][0] = fmaf(xa.x, w_cur[0].x, accg[r][0]);                   \
            accg[r][1] = fmaf(xa.x, w_cur[0].y, accg[r][1]);                   \
            accg[r][0] = fmaf(xa.y, w_cur[1].x, accg[r][0]);                   \
            accg[r][1] = fmaf(xa.y, w_cur[1].y, accg[r][1]);                   \
            accg[r][0] = fmaf(xa.z, w_cur[2].x, accg[r][0]);                   \
            accg[r][1] = fmaf(xa.z, w_cur[2].y, accg[r][1]);                   \
            accg[r][0] = fmaf(xa.w, w_cur[3].x, accg[r][0]);                   \
            accg[r][1] = fmaf(xa.w, w_cur[3].y, accg[r][1]);                   \
            accg[r][0] = fmaf(xb.x, w_cur[4].x, accg[r][0]);                   \
            accg[r][1] = fmaf(xb.x, w_cur[4].y, accg[r][1]);                   \
            accg[r][0] = fmaf(xb.y, w_cur[5].x, accg[r][0]);                   \
            accg[r][1] = fmaf(xb.y, w_cur[5].y, accg[r][1]);                   \
            accg[r][0] = fmaf(xb.z, w_cur[6].x, accg[r][0]);                   \
            accg[r][1] = fmaf(xb.z, w_cur[6].y, accg[r][1]);                   \
            accg[r][0] = fmaf(xb.w, w_cur[7].x, accg[r][0]);                   \
            accg[r][1] = fmaf(xb.w, w_cur[7].y, accg[r][1]);                   \
        }                                                                      \
    }

__global__ __launch_bounds__(512, 2) void rnn_fused3(
    const float* __restrict__ X,     // (32768, 512)
    const float* __restrict__ Wx,    // (512, 512)
    const float* __restrict__ bias,  // (512,)
    const float* __restrict__ Wh,    // (512, 512)
    const float* __restrict__ h0,    // (64, 512)
    float* __restrict__ out,         // (64, 512, 512) -- receives h only
    unsigned long long* __restrict__ hbuf)  // (2, 64, 512) tagged h (d_ws)
{
    __shared__ float xwtile[2][64][128];   // 64 KB: xw tile ring
    __shared__ float hslice[8][64];        //  2 KB
    __shared__ float partb[2][8][128];     //  4 KB
    __shared__ float xstage[2][64][8];     //  4 KB

    const int bid  = blockIdx.x;
    const int xcd  = bid & 7;
    const int idx  = bid >> 3;
    const int seq  = xcd * 8 + (idx & 7);
    const int part = idx >> 3;               // 0..3
    const int tid  = threadIdx.x;
    const int lane = tid & 63;
    const int s    = tid >> 6;                // wave 0..7
    const int colbase = part * 128;
    const int c0   = colbase + lane * 2;

    // ---- ring weights: Wh k-slice [s*64,+64) x 128 cols, register-pinned ----
    v2f wv[64];
    #pragma unroll
    for (int k = 0; k < 64; ++k)
        wv[k] = *(const v2f*)&Wh[(size_t)(s * 64 + k) * DH + c0];
    #pragma unroll
    for (int k = 0; k < 64; ++k)
        asm volatile("" : "+v"(wv[k]));

    const int rwave = s - 2 * part;
    const bool is_reducer = (rwave == 0) | (rwave == 1);
    const int q     = rwave * 64 + lane;      // col within part (reducer only)
    const int mycol = colbase + q;            // == slot for reducer waves
    const int slot  = s * 64 + lane;          // h index this lane feeds

    hslice[s][lane] = h0[(size_t)seq * DH + slot];
    const float bias_r = is_reducer ? bias[mycol] : 0.0f;

    float* __restrict__ outn = out + (size_t)seq * TSTEPS * DH;
    const float* __restrict__ Xn = X + (size_t)seq * TSTEPS * DH;

    // ---- GEMM thread mapping ----
    const int gc  = lane;        // local col pair (2gc, 2gc+1) -- Wx cols c0
    const int rg  = s;           // local rows rg*8 .. rg*8+7
    const int sxr = tid >> 3, sxk = tid & 7;   // X stage: [row][k]

    float accg[8][2];
    #pragma unroll
    for (int r = 0; r < 8; ++r) { accg[r][0] = 0.0f; accg[r][1] = 0.0f; }

    float2 w_cur[8], w_nxt[8];
    float  px_cur, px_nxt;

    // ---------------- prologue: build xw tile 0 (pipelined) ------------------
    px_cur = Xn[(size_t)sxr * DH + sxk];
    #pragma unroll
    for (int kk = 0; kk < 8; ++kk)
        w_cur[kk] = *(const float2*)&Wx[(size_t)kk * DH + c0];
    for (int u = 0; u < 64; ++u) {
        if (u < 63) {
            px_nxt = Xn[(size_t)sxr * DH + (u + 1) * 8 + sxk];
            #pragma unroll
            for (int kk = 0; kk < 8; ++kk)
                w_nxt[kk] = *(const float2*)&Wx[(size_t)((u + 1) * 8 + kk) * DH + c0];
        }
        xstage[u & 1][sxr][sxk] = px_cur;   // waits only px_cur (1-iter old)
        __syncthreads();
        GEMM_CHUNK_REG(u & 1);
        if (u < 63) {
            px_cur = px_nxt;
            #pragma unroll
            for (int kk = 0; kk < 8; ++kk) w_cur[kk] = w_nxt[kk];
        }
    }
    #pragma unroll
    for (int r = 0; r < 8; ++r) {
        float2 v; v.x = accg[r][0]; v.y = accg[r][1];
        *(float2*)&xwtile[0][rg * 8 + r][gc * 2] = v;
        accg[r][0] = 0.0f; accg[r][1] = 0.0f;
    }
    __syncthreads();

    // prefetch chunk for ring step 0 (tile 1, chunk 0)
    px_cur = Xn[(size_t)(64 + sxr) * DH + sxk];
    #pragma unroll
    for (int kk = 0; kk < 8; ++kk)
        w_cur[kk] = *(const float2*)&Wx[(size_t)kk * DH + c0];

    // ---------------- ring (R5 protocol + in-ring GEMM) ----------------------
    for (int t = 0; t < TSTEPS; ++t) {
        const int buf = t & 1;
        const int tb  = (t >> 6) + 1;        // tile being built this period
        const int u   = t & 63;              // chunk index
        const bool building = (tb < 8);
        const bool bnext    = (t < 447);     // chunk exists for step t+1

        // ---- ring FMA over own k-slice (all 8 waves) ----
        v2f acc = {0.0f, 0.0f};
        #pragma unroll
        for (int qq = 0; qq < 16; ++qq) {
            const float4 h4 = *(const float4*)&hslice[s][qq * 4];
            v2f hb;
            hb.x = h4.x; hb.y = h4.x; acc = __builtin_elementwise_fma(hb, wv[4*qq+0], acc);
            hb.x = h4.y; hb.y = h4.y; acc = __builtin_elementwise_fma(hb, wv[4*qq+1], acc);
            hb.x = h4.z; hb.y = h4.z; acc = __builtin_elementwise_fma(hb, wv[4*qq+2], acc);
            hb.x = h4.w; hb.y = h4.w; acc = __builtin_elementwise_fma(hb, wv[4*qq+3], acc);
        }
        *(v2f*)&partb[buf][s][lane * 2] = acc;

        // ---- stage X chunk from prefetched reg (vmcnt ~free: loaded @t-1) ----
        if (building) xstage[buf][sxr][sxk] = px_cur;

        // ---- issue next chunk's loads (hidden under transit window) ----
        if (bnext) {
            const int tb2 = ((t + 1) >> 6) + 1;
            const int u2  = (t + 1) & 63;
            px_nxt = Xn[(size_t)(tb2 * 64 + sxr) * DH + u2 * 8 + sxk];
            #pragma unroll
            for (int kk = 0; kk < 8; ++kk)
                w_nxt[kk] = *(const float2*)&Wx[(size_t)(u2 * 8 + kk) * DH + c0];
        }
        __syncthreads();   // the only barrier per step

        unsigned long long* hb64 = &hbuf[((size_t)buf * NSEQ + seq) * DH];
        if (is_reducer) {
            // xw from LDS tile; same assoc as R12: (acc_gemm + b) + ssum
            const float xwv = xwtile[(t >> 6) & 1][u][q] + bias_r;
            float ssum = partb[buf][0][q] + partb[buf][1][q]
                       + partb[buf][2][q] + partb[buf][3][q]
                       + partb[buf][4][q] + partb[buf][5][q]
                       + partb[buf][6][q] + partb[buf][7][q];
            const float hval = tanhf(xwv + ssum);
            if (t < TSTEPS - 1) {
                const unsigned long long v =
                    ((unsigned long long)(unsigned)(t + 1) << 32) |
                    (unsigned long long)__float_as_uint(hval);
                __hip_atomic_store(&hb64[mycol], v,
                                   __ATOMIC_RELAXED, __HIP_MEMORY_SCOPE_AGENT);
            }
            hslice[s][lane] = hval;           // own next-step data (slot==mycol)
            outn[(size_t)t * DH + mycol] = hval;   // fire-and-forget h store
        }

        // ---- in-ring GEMM: chunk u of tile tb (idle-window work) ----
        if (building) {
            GEMM_CHUNK_REG(buf);
            if (u == 63) {                   // tile complete -> LDS xw ring
                #pragma unroll
                for (int r = 0; r < 8; ++r) {
                    float2 v; v.x = accg[r][0]; v.y = accg[r][1];
                    *(float2*)&xwtile[tb & 1][rg * 8 + r][gc * 2] = v;
                    accg[r][0] = 0.0f; accg[r][1] = 0.0f;
                }
            }
        }

        // ---- non-reducers: poll own tagged slot (R5 verbatim) ----
        if (!is_reducer && t < TSTEPS - 1) {
            unsigned long long v;
            do {
                v = __hip_atomic_load(&hb64[slot], __ATOMIC_RELAXED,
                                      __HIP_MEMORY_SCOPE_AGENT);
            } while ((unsigned)(v >> 32) < (unsigned)(t + 1));
            hslice[s][lane] = __uint_as_float((unsigned)v);
        }

        // ---- rotate prefetch buffers (w_nxt long arrived by here) ----
        if (bnext) {
            px_cur = px_nxt;
            #pragma unroll
            for (int kk = 0; kk < 8; ++kk) w_cur[kk] = w_nxt[kk];
        }
        // no second barrier: hslice wave-private, partb/xstage double-buffered
    }
}

// =================== Fallback pair (small ws) ================================
__global__ __launch_bounds__(256) void xw_gemm(
    const float* __restrict__ X, const float* __restrict__ Wx,
    const float* __restrict__ b, float* __restrict__ XW)
{
    __shared__ float As[16][64];
    __shared__ float Bs[16][64];
    const int bm = blockIdx.x * 64, bn = blockIdx.y * 64;
    const int tid = threadIdx.x, tr = tid >> 4, tc = tid & 15;
    float acc[4][4] = {};
    for (int k0 = 0; k0 < DH; k0 += 16) {
        { int m = tid >> 2, kk = (tid & 3) * 4;
          const float4 v = *(const float4*)&X[(size_t)(bm + m) * DH + k0 + kk];
          As[kk][m]=v.x; As[kk+1][m]=v.y; As[kk+2][m]=v.z; As[kk+3][m]=v.w; }
        { int k = tid >> 4, j4 = (tid & 15) * 4;
          *(float4*)&Bs[k][j4] = *(const float4*)&Wx[(size_t)(k0 + k) * DH + bn + j4]; }
        __syncthreads();
        #pragma unroll
        for (int k = 0; k < 16; ++k) {
            float a0=As[k][tr*4],a1=As[k][tr*4+1],a2=As[k][tr*4+2],a3=As[k][tr*4+3];
            float b0=Bs[k][tc*4],b1=Bs[k][tc*4+1],b2=Bs[k][tc*4+2],b3=Bs[k][tc*4+3];
            acc[0][0]+=a0*b0;acc[0][1]+=a0*b1;acc[0][2]+=a0*b2;acc[0][3]+=a0*b3;
            acc[1][0]+=a1*b0;acc[1][1]+=a1*b1;acc[1][2]+=a1*b2;acc[1][3]+=a1*b3;
            acc[2][0]+=a2*b0;acc[2][1]+=a2*b1;acc[2][2]+=a2*b2;acc[2][3]+=a2*b3;
            acc[3][0]+=a3*b0;acc[3][1]+=a3*b1;acc[3][2]+=a3*b2;acc[3][3]+=a3*b3;
        }
        __syncthreads();
    }
    #pragma unroll
    for (int i = 0; i < 4; ++i) {
        const size_t row = (size_t)(bm + tr * 4 + i);
        #pragma unroll
        for (int j = 0; j < 4; ++j)
            XW[row * DH + bn + tc * 4 + j] = acc[i][j] + b[bn + tc * 4 + j];
    }
}

__global__ __launch_bounds__(1024) void rnn_rec(
    const float* __restrict__ Wh, const float* __restrict__ h0,
    float* __restrict__ out)
{
    __shared__ float hsh[DH];
    __shared__ float part[8][DH];
    const int n = blockIdx.x, tid = threadIdx.x;
    const int jgrp = tid & 127, ks = tid >> 7, kbase = ks * 64;
    if (tid < DH) hsh[tid] = h0[(size_t)n * DH + tid];
    __syncthreads();
    const float4* __restrict__ Wh4 = (const float4*)Wh;
    float* __restrict__ outn = out + (size_t)n * TSTEPS * DH;
    float xw_cur = (tid < DH) ? outn[tid] : 0.0f;
    for (int t = 0; t < TSTEPS; ++t) {
        float xw_next = 0.0f;
        if (tid < DH && t < TSTEPS - 1) xw_next = outn[(size_t)(t + 1) * DH + tid];
        float4 acc = {0,0,0,0};
        #pragma unroll 8
        for (int k = 0; k < 64; ++k) {
            const float hk = hsh[kbase + k];
            const float4 w = Wh4[(size_t)(kbase + k) * 128 + jgrp];
            acc.x += hk*w.x; acc.y += hk*w.y; acc.z += hk*w.z; acc.w += hk*w.w;
        }
        *(float4*)&part[ks][jgrp * 4] = acc;
        __syncthreads();
        if (tid < DH) {
            float sum = part[0][tid]+part[1][tid]+part[2][tid]+part[3][tid]
                      + part[4][tid]+part[5][tid]+part[6][tid]+part[7][tid];
            const float hv = tanhf(xw_cur + sum);
            hsh[tid] = hv;
            outn[(size_t)t * DH + tid] = hv;
            xw_cur = xw_next;
        }
        __syncthreads();
    }
}

extern "C" void kernel_launch(void* const* d_in, const int* in_sizes, int n_in,
                              void* d_out, int out_size, void* d_ws, size_t ws_size,
                              hipStream_t stream) {
    const float* x  = (const float*)d_in[0];  // (64, 512, 512)
    const float* h0 = (const float*)d_in[1];  // (64, 512)
    const float* Wx = (const float*)d_in[2];  // (512, 512)
    const float* Wh = (const float*)d_in[3];  // (512, 512)
    const float* b  = (const float*)d_in[4];  // (512,)
    float* out = (float*)d_out;               // (64, 512, 512)

    // Workspace: hbuf = (2, 64, 512) u64 tagged slots = 512 KB, zeroed per
    // launch (tag 0 < 1 => step-0 polls can't see stale; graph-replay safe).
    const size_t hbuf_bytes = (size_t)2 * NSEQ * DH * sizeof(unsigned long long);
    if (ws_size >= hbuf_bytes) {
        unsigned long long* hbuf = (unsigned long long*)d_ws;
        hipMemsetAsync(hbuf, 0, hbuf_bytes, stream);
        rnn_fused3<<<256, 512, 0, stream>>>(x, Wx, b, Wh, h0, out, hbuf);
    } else {
        xw_gemm<<<dim3(MTOT / 64, DH / 64), 256, 0, stream>>>(x, Wx, b, out);
        rnn_rec<<<NSEQ, 1024, 0, stream>>>(Wh, h0, out);
    }
}

// Round 14
// 782.664 us; speedup vs baseline: 1.0705x; 1.0705x over previous
//
#include <hip/hip_runtime.h>
#include <hip/hip_bf16.h>
#include <cmath>

// Problem: N=64, T=512, D=512, H=512
//   xw = x @ Wx + b ; h_t = tanh(xw_t + h_{t-1} @ Wh)
//
// R14 = R12 VERBATIM (best measured: 793us total). Self-fused ring:
// 256 wgs x 512 thr; wg (seq,part) runs the R5 h-exchange ring (tagged 8B
// {tag,h} words, relaxed agent atomics at the L3 coherence point, double
// buffered, one barrier/step) AND builds its own xw slice in the ring's
// ~1600cy transit windows (64x128 tile per 64 steps, K chunked by 8;
// X + Wx staged through LDS -- staging amortizes wave-redundant loads,
// proven by R13's 8x-L2-traffic regression when removed).
//
// CLOSED dead ends (all measured slower than this structure):
//  R6  sc0-load L2 exchange        -> stale-L1 spin, 24ms
//  R7  2-seq/wg latency hiding     -> 1143us (stale prefetch, 2 rings/wg)
//  R8  wg-scope atomic-RMW L2 path -> 797us (timed out to L3 anyway)
//  R9  contribution-passing        -> 1481us (3x publish volume, later publish)
//  R10 drain-free barrier+pipeline -> 777us (vmcnt guard moved ON-path)
//  R11 separate gated producer grid-> DEADLOCK (G16 co-residency violation)
//  R13 wstage removal              -> 837us (8x L2 Wx traffic, VGPR 128)
// Residual cost: 512 sequential L3 round-trips ~= 2500cy/step. Fabric
// latency floor for a cross-CU recurrence; not BW/compute bound
// (VALUBusy 39%, HBM 4.6%, 0 bank conflicts).

#define DH     512
#define NSEQ   64
#define TSTEPS 512
#define MTOT   32768   // N*T

typedef float v2f __attribute__((ext_vector_type(2)));

// 8k-chunk GEMM micro-tile: accg[8][2] += xstage[SB] (8 rows/wave) x wstage[SB]
#define GEMM_CHUNK(SB)                                                         \
    {                                                                          \
        float2 w2[8];                                                          \
        _Pragma("unroll")                                                      \
        for (int kk = 0; kk < 8; ++kk)                                         \
            w2[kk] = *(const float2*)&wstage[SB][kk][gc * 2];                  \
        _Pragma("unroll")                                                      \
        for (int r = 0; r < 8; ++r) {                                          \
            const float4 xa = *(const float4*)&xstage[SB][rg * 8 + r][0];      \
            const float4 xb = *(const float4*)&xstage[SB][rg * 8 + r][4];      \
            accg[r][0] = fmaf(xa.x, w2[0].x, accg[r][0]);                      \
            accg[r][1] = fmaf(xa.x, w2[0].y, accg[r][1]);                      \
            accg[r][0] = fmaf(xa.y, w2[1].x, accg[r][0]);                      \
            accg[r][1] = fmaf(xa.y, w2[1].y, accg[r][1]);                      \
            accg[r][0] = fmaf(xa.z, w2[2].x, accg[r][0]);                      \
            accg[r][1] = fmaf(xa.z, w2[2].y, accg[r][1]);                      \
            accg[r][0] = fmaf(xa.w, w2[3].x, accg[r][0]);                      \
            accg[r][1] = fmaf(xa.w, w2[3].y, accg[r][1]);                      \
            accg[r][0] = fmaf(xb.x, w2[4].x, accg[r][0]);                      \
            accg[r][1] = fmaf(xb.x, w2[4].y, accg[r][1]);                      \
            accg[r][0] = fmaf(xb.y, w2[5].x, accg[r][0]);                      \
            accg[r][1] = fmaf(xb.y, w2[5].y, accg[r][1]);                      \
            accg[r][0] = fmaf(xb.z, w2[6].x, accg[r][0]);                      \
            accg[r][1] = fmaf(xb.z, w2[6].y, accg[r][1]);                      \
            accg[r][0] = fmaf(xb.w, w2[7].x, accg[r][0]);                      \
            accg[r][1] = fmaf(xb.w, w2[7].y, accg[r][1]);                      \
        }                                                                      \
    }

__global__ __launch_bounds__(512, 2) void rnn_fused2(
    const float* __restrict__ X,     // (32768, 512)
    const float* __restrict__ Wx,    // (512, 512)
    const float* __restrict__ bias,  // (512,)
    const float* __restrict__ Wh,    // (512, 512)
    const float* __restrict__ h0,    // (64, 512)
    float* __restrict__ out,         // (64, 512, 512) -- receives h only
    unsigned long long* __restrict__ hbuf)  // (2, 64, 512) tagged h (d_ws)
{
    __shared__ float xwtile[2][64][128];   // 64 KB: xw tile ring (tile rb -> buf rb&1)
    __shared__ float hslice[8][64];        //  2 KB: wave-private h slices
    __shared__ float partb[2][8][128];     //  4 KB: ring partials (dbuf by t&1)
    __shared__ float xstage[2][64][8];     //  4 KB: X chunk stage (dbuf by t&1)
    __shared__ float wstage[2][8][128];    //  8 KB: Wx chunk stage

    const int bid  = blockIdx.x;
    const int xcd  = bid & 7;
    const int idx  = bid >> 3;
    const int seq  = xcd * 8 + (idx & 7);
    const int part = idx >> 3;               // 0..3
    const int tid  = threadIdx.x;
    const int lane = tid & 63;
    const int s    = tid >> 6;                // wave 0..7
    const int colbase = part * 128;
    const int c0   = colbase + lane * 2;

    // ---- ring weights: Wh k-slice [s*64,+64) x 128 cols, register-pinned ----
    v2f wv[64];
    #pragma unroll
    for (int k = 0; k < 64; ++k)
        wv[k] = *(const v2f*)&Wh[(size_t)(s * 64 + k) * DH + c0];
    #pragma unroll
    for (int k = 0; k < 64; ++k)
        asm volatile("" : "+v"(wv[k]));

    const int rwave = s - 2 * part;
    const bool is_reducer = (rwave == 0) | (rwave == 1);
    const int q     = rwave * 64 + lane;      // col within part (reducer only)
    const int mycol = colbase + q;            // == slot for reducer waves
    const int slot  = s * 64 + lane;          // h index this lane feeds

    hslice[s][lane] = h0[(size_t)seq * DH + slot];
    const float bias_r = is_reducer ? bias[mycol] : 0.0f;

    float* __restrict__ outn = out + (size_t)seq * TSTEPS * DH;
    const float* __restrict__ Xn = X + (size_t)seq * TSTEPS * DH;

    // ---- GEMM thread mapping ----
    const int gc  = lane;        // local col pair (2gc, 2gc+1)
    const int rg  = s;           // local rows rg*8 .. rg*8+7
    const int sxr = tid >> 3, sxk = tid & 7;   // X stage: [row][k]
    const int swk = tid >> 6, swc = tid & 63;  // Wx stage: [k][colpair]

    float accg[8][2];
    #pragma unroll
    for (int r = 0; r < 8; ++r) { accg[r][0] = 0.0f; accg[r][1] = 0.0f; }

    // ---------------- prologue: build xw tile 0 ------------------------------
    for (int u = 0; u < 64; ++u) {
        const float  pxv = Xn[(size_t)sxr * DH + u * 8 + sxk];
        const float2 pwv = *(const float2*)&Wx[(size_t)(u * 8 + swk) * DH + colbase + swc * 2];
        xstage[u & 1][sxr][sxk] = pxv;
        *(float2*)&wstage[u & 1][swk][swc * 2] = pwv;
        __syncthreads();
        GEMM_CHUNK(u & 1);
    }
    #pragma unroll
    for (int r = 0; r < 8; ++r) {
        float2 v; v.x = accg[r][0]; v.y = accg[r][1];
        *(float2*)&xwtile[0][rg * 8 + r][gc * 2] = v;
        accg[r][0] = 0.0f; accg[r][1] = 0.0f;
    }
    __syncthreads();

    // prefetch stage chunk for ring step 0 (tile 1, chunk 0)
    float  pxv = Xn[(size_t)(64 + sxr) * DH + sxk];
    float2 pwv = *(const float2*)&Wx[(size_t)swk * DH + colbase + swc * 2];

    // ---------------- ring (R5 protocol + in-ring GEMM) ----------------------
    for (int t = 0; t < TSTEPS; ++t) {
        const int buf = t & 1;
        const int tb  = (t >> 6) + 1;        // tile being built this period
        const int u   = t & 63;              // chunk index
        const bool building = (tb < 8);

        // ---- ring FMA over own k-slice (all 8 waves) ----
        v2f acc = {0.0f, 0.0f};
        #pragma unroll
        for (int qq = 0; qq < 16; ++qq) {
            const float4 h4 = *(const float4*)&hslice[s][qq * 4];
            v2f hb;
            hb.x = h4.x; hb.y = h4.x; acc = __builtin_elementwise_fma(hb, wv[4*qq+0], acc);
            hb.x = h4.y; hb.y = h4.y; acc = __builtin_elementwise_fma(hb, wv[4*qq+1], acc);
            hb.x = h4.z; hb.y = h4.z; acc = __builtin_elementwise_fma(hb, wv[4*qq+2], acc);
            hb.x = h4.w; hb.y = h4.w; acc = __builtin_elementwise_fma(hb, wv[4*qq+3], acc);
        }
        *(v2f*)&partb[buf][s][lane * 2] = acc;

        // ---- stage writes from prefetched regs (vmcnt ~free: loaded @t-1) ----
        if (building) {
            xstage[buf][sxr][sxk] = pxv;
            *(float2*)&wstage[buf][swk][swc * 2] = pwv;
        }
        __syncthreads();   // the only barrier per step

        unsigned long long* hb64 = &hbuf[((size_t)buf * NSEQ + seq) * DH];
        if (is_reducer) {
            // xw from LDS tile; assoc: (acc_gemm + b) + ssum
            const float xwv = xwtile[(t >> 6) & 1][u][q] + bias_r;
            float ssum = partb[buf][0][q] + partb[buf][1][q]
                       + partb[buf][2][q] + partb[buf][3][q]
                       + partb[buf][4][q] + partb[buf][5][q]
                       + partb[buf][6][q] + partb[buf][7][q];
            const float hval = tanhf(xwv + ssum);
            if (t < TSTEPS - 1) {
                const unsigned long long v =
                    ((unsigned long long)(unsigned)(t + 1) << 32) |
                    (unsigned long long)__float_as_uint(hval);
                __hip_atomic_store(&hb64[mycol], v,
                                   __ATOMIC_RELAXED, __HIP_MEMORY_SCOPE_AGENT);
            }
            hslice[s][lane] = hval;           // own next-step data (slot==mycol)
            outn[(size_t)t * DH + mycol] = hval;   // fire-and-forget h store
        }

        // ---- prefetch next step's stage chunk (hidden in transit window) ----
        if (building && t < 447) {           // chunk for step t+1 exists
            const int tb2 = ((t + 1) >> 6) + 1;
            const int u2  = (t + 1) & 63;
            pxv = Xn[(size_t)(tb2 * 64 + sxr) * DH + u2 * 8 + sxk];
            pwv = *(const float2*)&Wx[(size_t)(u2 * 8 + swk) * DH + colbase + swc * 2];
        }

        // ---- in-ring GEMM: chunk u of tile tb (all waves; idle-window) ----
        if (building) {
            GEMM_CHUNK(buf);
            if (u == 63) {                   // tile complete -> LDS xw ring
                #pragma unroll
                for (int r = 0; r < 8; ++r) {
                    float2 v; v.x = accg[r][0]; v.y = accg[r][1];
                    *(float2*)&xwtile[tb & 1][rg * 8 + r][gc * 2] = v;
                    accg[r][0] = 0.0f; accg[r][1] = 0.0f;
                }
            }
        }

        // ---- non-reducers: poll own tagged slot (R5 verbatim) ----
        if (!is_reducer && t < TSTEPS - 1) {
            unsigned long long v;
            do {
                v = __hip_atomic_load(&hb64[slot], __ATOMIC_RELAXED,
                                      __HIP_MEMORY_SCOPE_AGENT);
            } while ((unsigned)(v >> 32) < (unsigned)(t + 1));
            hslice[s][lane] = __uint_as_float((unsigned)v);
        }
        // no second barrier: hslice wave-private, partb/stage double-buffered
    }
}

// =================== Fallback pair (small ws) ================================
__global__ __launch_bounds__(256) void xw_gemm(
    const float* __restrict__ X, const float* __restrict__ Wx,
    const float* __restrict__ b, float* __restrict__ XW)
{
    __shared__ float As[16][64];
    __shared__ float Bs[16][64];
    const int bm = blockIdx.x * 64, bn = blockIdx.y * 64;
    const int tid = threadIdx.x, tr = tid >> 4, tc = tid & 15;
    float acc[4][4] = {};
    for (int k0 = 0; k0 < DH; k0 += 16) {
        { int m = tid >> 2, kk = (tid & 3) * 4;
          const float4 v = *(const float4*)&X[(size_t)(bm + m) * DH + k0 + kk];
          As[kk][m]=v.x; As[kk+1][m]=v.y; As[kk+2][m]=v.z; As[kk+3][m]=v.w; }
        { int k = tid >> 4, j4 = (tid & 15) * 4;
          *(float4*)&Bs[k][j4] = *(const float4*)&Wx[(size_t)(k0 + k) * DH + bn + j4]; }
        __syncthreads();
        #pragma unroll
        for (int k = 0; k < 16; ++k) {
            float a0=As[k][tr*4],a1=As[k][tr*4+1],a2=As[k][tr*4+2],a3=As[k][tr*4+3];
            float b0=Bs[k][tc*4],b1=Bs[k][tc*4+1],b2=Bs[k][tc*4+2],b3=Bs[k][tc*4+3];
            acc[0][0]+=a0*b0;acc[0][1]+=a0*b1;acc[0][2]+=a0*b2;acc[0][3]+=a0*b3;
            acc[1][0]+=a1*b0;acc[1][1]+=a1*b1;acc[1][2]+=a1*b2;acc[1][3]+=a1*b3;
            acc[2][0]+=a2*b0;acc[2][1]+=a2*b1;acc[2][2]+=a2*b2;acc[2][3]+=a2*b3;
            acc[3][0]+=a3*b0;acc[3][1]+=a3*b1;acc[3][2]+=a3*b2;acc[3][3]+=a3*b3;
        }
        __syncthreads();
    }
    #pragma unroll
    for (int i = 0; i < 4; ++i) {
        const size_t row = (size_t)(bm + tr * 4 + i);
        #pragma unroll
        for (int j = 0; j < 4; ++j)
            XW[row * DH + bn + tc * 4 + j] = acc[i][j] + b[bn + tc * 4 + j];
    }
}

__global__ __launch_bounds__(1024) void rnn_rec(
    const float* __restrict__ Wh, const float* __restrict__ h0,
    float* __restrict__ out)
{
    __shared__ float hsh[DH];
    __shared__ float part[8][DH];
    const int n = blockIdx.x, tid = threadIdx.x;
    const int jgrp = tid & 127, ks = tid >> 7, kbase = ks * 64;
    if (tid < DH) hsh[tid] = h0[(size_t)n * DH + tid];
    __syncthreads();
    const float4* __restrict__ Wh4 = (const float4*)Wh;
    float* __restrict__ outn = out + (size_t)n * TSTEPS * DH;
    float xw_cur = (tid < DH) ? outn[tid] : 0.0f;
    for (int t = 0; t < TSTEPS; ++t) {
        float xw_next = 0.0f;
        if (tid < DH && t < TSTEPS - 1) xw_next = outn[(size_t)(t + 1) * DH + tid];
        float4 acc = {0,0,0,0};
        #pragma unroll 8
        for (int k = 0; k < 64; ++k) {
            const float hk = hsh[kbase + k];
            const float4 w = Wh4[(size_t)(kbase + k) * 128 + jgrp];
            acc.x += hk*w.x; acc.y += hk*w.y; acc.z += hk*w.z; acc.w += hk*w.w;
        }
        *(float4*)&part[ks][jgrp * 4] = acc;
        __syncthreads();
        if (tid < DH) {
            float sum = part[0][tid]+part[1][tid]+part[2][tid]+part[3][tid]
                      + part[4][tid]+part[5][tid]+part[6][tid]+part[7][tid];
            const float hv = tanhf(xw_cur + sum);
            hsh[tid] = hv;
            outn[(size_t)t * DH + tid] = hv;
            xw_cur = xw_next;
        }
        __syncthreads();
    }
}

extern "C" void kernel_launch(void* const* d_in, const int* in_sizes, int n_in,
                              void* d_out, int out_size, void* d_ws, size_t ws_size,
                              hipStream_t stream) {
    const float* x  = (const float*)d_in[0];  // (64, 512, 512)
    const float* h0 = (const float*)d_in[1];  // (64, 512)
    const float* Wx = (const float*)d_in[2];  // (512, 512)
    const float* Wh = (const float*)d_in[3];  // (512, 512)
    const float* b  = (const float*)d_in[4];  // (512,)
    float* out = (float*)d_out;               // (64, 512, 512)

    // Workspace: hbuf = (2, 64, 512) u64 tagged slots = 512 KB, zeroed per
    // launch (tag 0 < 1 => step-0 polls can't see stale; graph-replay safe).
    const size_t hbuf_bytes = (size_t)2 * NSEQ * DH * sizeof(unsigned long long);
    if (ws_size >= hbuf_bytes) {
        unsigned long long* hbuf = (unsigned long long*)d_ws;
        hipMemsetAsync(hbuf, 0, hbuf_bytes, stream);
        rnn_fused2<<<256, 512, 0, stream>>>(x, Wx, b, Wh, h0, out, hbuf);
    } else {
        xw_gemm<<<dim3(MTOT / 64, DH / 64), 256, 0, stream>>>(x, Wx, b, out);
        rnn_rec<<<NSEQ, 1024, 0, stream>>>(Wh, h0, out);
    }
}